// Round 9
// baseline (464.626 us; speedup 1.0000x reference)
//
#include <hip/hip_runtime.h>
#include <stdint.h>
#include <stddef.h>

#define TSEQ   2048
#define HDIM   512
#define NHEADS 8
#define HEADD  64
#define NVOCAB 32000
#define NROWS  4096   // B*T

typedef unsigned short ushort_t;
typedef __bf16 bf16x8 __attribute__((ext_vector_type(8)));
typedef float  f32x4  __attribute__((ext_vector_type(4)));
typedef unsigned short us8 __attribute__((ext_vector_type(8)));
typedef unsigned short us4 __attribute__((ext_vector_type(4)));
typedef unsigned short us2 __attribute__((ext_vector_type(2)));

__device__ __forceinline__ ushort_t f2bf(float f){
  union { float f; unsigned int u; } v; v.f = f;
  unsigned int u = v.u;
  u += 0x7FFFu + ((u >> 16) & 1u);   // RNE
  return (ushort_t)(u >> 16);
}

__device__ __forceinline__ void gload_lds16(const ushort_t* g, ushort_t* l){
  __builtin_amdgcn_global_load_lds(
      (const __attribute__((address_space(1))) void*)g,
      (__attribute__((address_space(3))) void*)l, 16, 0, 0);
}

// ---------------- fused f32 -> bf16 convert of all weights + bias concat ----------------
#define CVT_N4   4423680   // 5*65536 + 4096000
#define CVT_TOT  4424064   // + 384
__global__ void cvt_all_kernel(const float* __restrict__ Wprj, const float* __restrict__ Wq,
                               const float* __restrict__ Wk,   const float* __restrict__ Wv,
                               const float* __restrict__ W1,   const float* __restrict__ W2,
                               const float* __restrict__ bq,   const float* __restrict__ bk,
                               const float* __restrict__ bv,
                               ushort_t* __restrict__ wdst, float* __restrict__ bqkv){
  int stride = gridDim.x * blockDim.x;
  for (int i = blockIdx.x * blockDim.x + threadIdx.x; i < CVT_TOT; i += stride){
    if (i < CVT_N4){
      const float* src; int j;
      if (i < 327680){                       // the five 512x512 weights
        int w = i >> 16;                     // 0..4
        j = i & 65535;
        src = (w == 0) ? Wprj : (w == 1) ? Wq : (w == 2) ? Wk : (w == 3) ? Wv : W1;
      } else {
        j = i - 327680;
        src = W2;
      }
      float4 f = ((const float4*)src)[j];
      us4 o;
      o[0] = f2bf(f.x); o[1] = f2bf(f.y); o[2] = f2bf(f.z); o[3] = f2bf(f.w);
      ((us4*)wdst)[i] = o;
    } else {
      int j = i - CVT_N4;                    // 0..383 float4 of bqkv
      const float* src = (j < 128) ? bq : (j < 256) ? bk : bv;
      int jj = j & 127;
      ((float4*)bqkv)[j] = ((const float4*)src)[jj];
    }
  }
}

// ---------------- embedding: x0 = tok[ix] + pos ----------------
__global__ void embed_kernel(const int* __restrict__ ixs, const float* __restrict__ tok,
                             const float* __restrict__ pos, ushort_t* __restrict__ x0){
  const int r = blockIdx.x;            // 0..4095 (b*T + t)
  const int t = r & (TSEQ - 1);
  const int ix = ixs[r];
  const int j = threadIdx.x;           // 0..255, 2 floats each
  const float2 a = ((const float2*)(tok + (size_t)ix * HDIM))[j];
  const float2 p = ((const float2*)(pos + (size_t)t * HDIM))[j];
  us2 o; o[0] = f2bf(a.x + p.x); o[1] = f2bf(a.y + p.y);
  *(us2*)(x0 + (size_t)r * HDIM + j * 2) = o;
}

// ---------------- small GEMM: C[M,N] = A[M,K] @ W[N,K]^T (+bias)(+relu) ----------------
// 128x128 tile, BK=64, double-buffered LDS, XOR chunk swizzle (conflicts=0 per r5).
// MFMA operands SWAPPED (mfma(bfr, af)): lane holds 4 consecutive output columns
// -> vectorized us4/f32x4 epilogue. (Verified passing r6/r8.)
template<int HAS_BIAS, int RELU, int OUT_F32>
__global__ __launch_bounds__(256) void gemm2_kernel(
    const ushort_t* __restrict__ A, const ushort_t* __restrict__ W,
    const float* __restrict__ bias, void* __restrict__ outp,
    int M, int N, int K)
{
  __shared__ ushort_t As[2][128 * 64];
  __shared__ ushort_t Bs[2][128 * 64];
  const int tid  = threadIdx.x;
  const int wave = tid >> 6;
  const int lane = tid & 63;
  const int lr   = lane & 15;
  const int lg   = lane >> 4;
  const int wr   = wave >> 1, wc = wave & 1;

  const int nwg = gridDim.x;
  const int cpx = nwg >> 3;                    // blocks per XCD chunk
  const int g   = (blockIdx.x & 7) * cpx + (blockIdx.x >> 3);
  const int nby = M >> 7;
  const int by  = g % nby;
  const int bx  = g / nby;
  const int row0 = by << 7;
  const int col0 = bx << 7;

  f32x4 acc[4][4];
#pragma unroll
  for (int m = 0; m < 4; m++)
#pragma unroll
    for (int n = 0; n < 4; n++) acc[m][n] = (f32x4){0.f, 0.f, 0.f, 0.f};

  const int e    = tid * 8;
  const int srow = e >> 6;
  const int gch  = (((e & 63) >> 3) ^ (srow & 7)) * 8;
  const ushort_t* gA = A + (size_t)(row0 + srow) * K + gch;
  const ushort_t* gB = W + (size_t)(col0 + srow) * K + gch;
  const int ldsoff = wave * 512;

#pragma unroll
  for (int p = 0; p < 4; p++){
    gload_lds16(gA + (size_t)(p * 32) * K, &As[0][p * 2048 + ldsoff]);
    gload_lds16(gB + (size_t)(p * 32) * K, &Bs[0][p * 2048 + ldsoff]);
  }
  __syncthreads();

  const int NT = K >> 6;
  for (int t = 0; t < NT; ++t){
    const int cur = t & 1;
    if (t + 1 < NT){
      const int ko = (t + 1) << 6;
#pragma unroll
      for (int p = 0; p < 4; p++){
        gload_lds16(gA + (size_t)(p * 32) * K + ko, &As[cur ^ 1][p * 2048 + ldsoff]);
        gload_lds16(gB + (size_t)(p * 32) * K + ko, &Bs[cur ^ 1][p * 2048 + ldsoff]);
      }
    }
#pragma unroll
    for (int kk = 0; kk < 64; kk += 32){
      const int rch = (((kk >> 3) + lg) ^ (lr & 7)) * 8;   // swizzled read chunk
      bf16x8 af[4], bfr[4];
#pragma unroll
      for (int m = 0; m < 4; m++)
        af[m] = __builtin_bit_cast(bf16x8,
            *(const us8*)&As[cur][(wr * 64 + m * 16 + lr) * 64 + rch]);
#pragma unroll
      for (int n = 0; n < 4; n++)
        bfr[n] = __builtin_bit_cast(bf16x8,
            *(const us8*)&Bs[cur][(wc * 64 + n * 16 + lr) * 64 + rch]);
#pragma unroll
      for (int m = 0; m < 4; m++)
#pragma unroll
        for (int n = 0; n < 4; n++)
          acc[m][n] = __builtin_amdgcn_mfma_f32_16x16x32_bf16(bfr[n], af[m], acc[m][n], 0, 0, 0);
    }
    __syncthreads();
  }

  // epilogue: lane holds rows (wr*64+m*16+lr), cols (wc*64+n*16+lg*4 .. +3)
#pragma unroll
  for (int n = 0; n < 4; n++){
    const int colb = col0 + wc * 64 + n * 16 + lg * 4;
    f32x4 b4 = (f32x4){0.f, 0.f, 0.f, 0.f};
    if (HAS_BIAS) b4 = *(const f32x4*)&bias[colb];
#pragma unroll
    for (int m = 0; m < 4; m++){
      const int row = row0 + wr * 64 + m * 16 + lr;
      float v0 = acc[m][n][0] + b4[0], v1 = acc[m][n][1] + b4[1];
      float v2 = acc[m][n][2] + b4[2], v3 = acc[m][n][3] + b4[3];
      if (RELU){ v0 = fmaxf(v0,0.f); v1 = fmaxf(v1,0.f); v2 = fmaxf(v2,0.f); v3 = fmaxf(v3,0.f); }
      if (OUT_F32){
        f32x4 o = {v0, v1, v2, v3};
        *(f32x4*)&((float*)outp)[(size_t)row * N + colb] = o;
      } else {
        us4 o; o[0] = f2bf(v0); o[1] = f2bf(v1); o[2] = f2bf(v2); o[3] = f2bf(v3);
        *(us4*)&((ushort_t*)outp)[(size_t)row * N + colb] = o;
      }
    }
  }
}

// ---------------- vocab GEMM (8-phase-style): out = relu(A @ W2^T + b2), f32 ----------------
// 256x256 tile, BK=64 (8 K-tiles), 8 waves (2Mx4N), double-buffered 128 KB LDS,
// 1 block/CU. 4 phases per K-tile, each {ds_read A-frags || issue 2 staged loads
// of tile t+1 -> s_barrier -> lgkmcnt(0) -> setprio(1) 16 MFMA setprio(0) ->
// s_barrier}. B-frags read once at ph0, held in regs. Counted vmcnt, never 0
// mid-loop: issue order B0,B1,B2,B3,A0,A2,A1,A3; vmcnt(4) end-ph1 (retires prior
// A1,A3), vmcnt(2) end-ph3 (retires B0-3,A0,A2 of t+1; leaves its A1,A3 in
// flight). Chunk-XOR swizzle ^(row&7) on 16B chunks (conflicts=0 per r5), both
// sides of the involution; LDS dest linear for global_load_lds. Normal stores
// (L2 write-back absorbs the bursts; NT regressed in r8). by-inner mapping:
// consecutive blocks share the W2 panel.
#define VNT2 8
__global__ __launch_bounds__(512, 1) void gemm_big_kernel(
    const ushort_t* __restrict__ A, const ushort_t* __restrict__ W,
    const float* __restrict__ bias, float* __restrict__ outp)
{
  __shared__ ushort_t As[2][256 * 64];
  __shared__ ushort_t Bs[2][256 * 64];
  const int K = HDIM, N = NVOCAB;
  const int tid  = threadIdx.x;
  const int wave = tid >> 6;            // 0..7
  const int lane = tid & 63;
  const int lr   = lane & 15;
  const int lg   = lane >> 4;
  const int wr   = wave >> 2;           // 0..1 (M)
  const int wc   = wave & 3;            // 0..3 (N)
  const int by   = blockIdx.x & 15;
  const int bx   = blockIdx.x >> 4;     // 0..124
  const int row0 = by << 8;
  const int col0 = bx << 8;

  // staging: pass p covers rows p*64..p*64+63; thread -> row (tid>>3), chunk tid&7
  const int srow8 = tid >> 3;                          // 0..63
  const int gch   = (((tid & 7) ^ (srow8 & 7))) * 8;   // swizzled source chunk
  const int ldsoff = wave * 512;                       // linear dest (elems)
  const ushort_t* gA = A + (size_t)(row0 + srow8) * K + gch;
  const ushort_t* gW = W + (size_t)(col0 + srow8) * K + gch;

  f32x4 acc[8][4];
#pragma unroll
  for (int m = 0; m < 8; m++)
#pragma unroll
    for (int n = 0; n < 4; n++) acc[m][n] = (f32x4){0.f, 0.f, 0.f, 0.f};

  // ---- prologue: stage tile 0 (order B0..B3, A0, A2, A1, A3), drain, barrier ----
#pragma unroll
  for (int p = 0; p < 4; p++)
    gload_lds16(gW + (size_t)(p * 64) * K, &Bs[0][p * 4096 + ldsoff]);
  gload_lds16(gA,                      &As[0][0 * 4096 + ldsoff]);
  gload_lds16(gA + (size_t)128 * K,    &As[0][2 * 4096 + ldsoff]);
  gload_lds16(gA + (size_t)64 * K,     &As[0][1 * 4096 + ldsoff]);
  gload_lds16(gA + (size_t)192 * K,    &As[0][3 * 4096 + ldsoff]);
  asm volatile("s_waitcnt vmcnt(0)" ::: "memory");
  __builtin_amdgcn_s_barrier();

  bf16x8 bfr[4][2];
  for (int t = 0; t < VNT2; ++t){
    const int cur = t & 1;
    const ushort_t* Ac = &As[cur][0];
    const ushort_t* Bc = &Bs[cur][0];
    ushort_t* An = &As[cur ^ 1][0];
    ushort_t* Bn = &Bs[cur ^ 1][0];
    const bool pf = (t + 1 < VNT2);
    const int kg = (t + 1) << 6;

#pragma unroll
    for (int p = 0; p < 4; ++p){
      // ---- ds_read this phase's fragments ----
      bf16x8 af[2][2];
#pragma unroll
      for (int mm = 0; mm < 2; mm++){
        const int R = wr * 128 + (2 * p + mm) * 16 + lr;
#pragma unroll
        for (int k2 = 0; k2 < 2; k2++){
          const int pos = ((k2 * 4 + lg) ^ (lr & 7)) * 8;
          af[mm][k2] = __builtin_bit_cast(bf16x8, *(const us8*)&Ac[R * 64 + pos]);
        }
      }
      if (p == 0){
#pragma unroll
        for (int n = 0; n < 4; n++){
          const int R = wc * 64 + n * 16 + lr;
#pragma unroll
          for (int k2 = 0; k2 < 2; k2++){
            const int pos = ((k2 * 4 + lg) ^ (lr & 7)) * 8;
            bfr[n][k2] = __builtin_bit_cast(bf16x8, *(const us8*)&Bc[R * 64 + pos]);
          }
        }
      }
      // ---- stage 2 loads of tile t+1 (issue order B0,B1 | B2,B3 | A0,A2 | A1,A3) ----
      if (pf){
        if (p == 0){
          gload_lds16(gW + (size_t)(0 * 64) * K + kg, &Bn[0 * 4096 + ldsoff]);
          gload_lds16(gW + (size_t)(1 * 64) * K + kg, &Bn[1 * 4096 + ldsoff]);
        } else if (p == 1){
          gload_lds16(gW + (size_t)(2 * 64) * K + kg, &Bn[2 * 4096 + ldsoff]);
          gload_lds16(gW + (size_t)(3 * 64) * K + kg, &Bn[3 * 4096 + ldsoff]);
        } else if (p == 2){
          gload_lds16(gA + kg,                   &An[0 * 4096 + ldsoff]);
          gload_lds16(gA + (size_t)128 * K + kg, &An[2 * 4096 + ldsoff]);
        } else {
          gload_lds16(gA + (size_t)64 * K + kg,  &An[1 * 4096 + ldsoff]);
          gload_lds16(gA + (size_t)192 * K + kg, &An[3 * 4096 + ldsoff]);
        }
      }
      __builtin_amdgcn_s_barrier();
      asm volatile("s_waitcnt lgkmcnt(0)" ::: "memory");
      __builtin_amdgcn_sched_barrier(0);
      __builtin_amdgcn_s_setprio(1);
#pragma unroll
      for (int mm = 0; mm < 2; mm++)
#pragma unroll
        for (int n = 0; n < 4; n++)
#pragma unroll
          for (int k2 = 0; k2 < 2; k2++)
            acc[2 * p + mm][n] = __builtin_amdgcn_mfma_f32_16x16x32_bf16(
                bfr[n][k2], af[mm][k2], acc[2 * p + mm][n], 0, 0, 0);
      __builtin_amdgcn_s_setprio(0);
      __builtin_amdgcn_sched_barrier(0);
      // counted waits: retire exactly what the upcoming phase consumes
      if (p == 1){ asm volatile("s_waitcnt vmcnt(4)" ::: "memory"); }
      if (p == 3){
        if (pf) { asm volatile("s_waitcnt vmcnt(2)" ::: "memory"); }
        else    { asm volatile("s_waitcnt vmcnt(0)" ::: "memory"); }
      }
      __builtin_amdgcn_s_barrier();
    }
  }

  // ---- epilogue: f32x4 stores (swapped-operand layout, verified r6/r8) ----
#pragma unroll
  for (int n = 0; n < 4; n++){
    const int colb = col0 + wc * 64 + n * 16 + lg * 4;
    const f32x4 b4 = *(const f32x4*)&bias[colb];
#pragma unroll
    for (int m = 0; m < 8; m++){
      const int row = row0 + wr * 128 + m * 16 + lr;
      f32x4 o;
      o[0] = fmaxf(acc[m][n][0] + b4[0], 0.f);
      o[1] = fmaxf(acc[m][n][1] + b4[1], 0.f);
      o[2] = fmaxf(acc[m][n][2] + b4[2], 0.f);
      o[3] = fmaxf(acc[m][n][3] + b4[3], 0.f);
      *(f32x4*)&outp[(size_t)row * N + colb] = o;
    }
  }
}

// ---------------- fused causal flash attention ----------------
// Heavy-first dispatch: qt = 31 - blockIdx.x (32:1 causal work spread).
__global__ __launch_bounds__(256) void attn_kernel(
    const ushort_t* __restrict__ qkv, ushort_t* __restrict__ y)
{
  __shared__ ushort_t Ks[64 * 64];
  __shared__ ushort_t Vt[64 * 64];     // transposed: [d][key]
  __shared__ ushort_t Ps[4][16 * 64];
  const int qt   = 31 - blockIdx.x;
  const int hb   = blockIdx.y;
  const int b    = hb >> 3;
  const int h    = hb & 7;
  const int tid  = threadIdx.x;
  const int wave = tid >> 6, lane = tid & 63;
  const int lr   = lane & 15, lg = lane >> 4;
  const int ld   = 3 * HDIM;
  const size_t rowbase = (size_t)b * TSEQ;
  const ushort_t* kb = qkv + HDIM;
  const ushort_t* vb = qkv + 2 * HDIM;

  const int qrow = qt * 64 + wave * 16 + lr;
  const ushort_t* qp = qkv + (rowbase + qrow) * ld + h * HEADD;
  bf16x8 qf[2];
  qf[0] = __builtin_bit_cast(bf16x8, *(const us8*)&qp[lg * 8]);
  qf[1] = __builtin_bit_cast(bf16x8, *(const us8*)&qp[32 + lg * 8]);

  float m_run[4], l_run[4];
  f32x4 acc_o[4];
#pragma unroll
  for (int i = 0; i < 4; i++){ m_run[i] = -1e30f; l_run[i] = 0.f; acc_o[i] = (f32x4){0,0,0,0}; }

  const int e    = tid * 8;
  const int srow = e >> 6;
  const int scol = e & 63;
  const float scale = 0.04419417382415922f;   // 1/sqrt(512) (full H per reference!)

  for (int kt = 0; kt <= qt; ++kt){
    const ushort_t* gK = kb + (rowbase + kt * 64 + srow) * ld + h * HEADD + scol;
    gload_lds16(gK,                     &Ks[wave * 512]);
    gload_lds16(gK + (size_t)32 * ld,   &Ks[2048 + wave * 512]);
    const ushort_t* gV = vb + (rowbase + kt * 64 + srow) * ld + h * HEADD + scol;
    us8 v0 = *(const us8*)gV;
    us8 v1 = *(const us8*)(gV + (size_t)32 * ld);
#pragma unroll
    for (int j = 0; j < 8; j++){
      Vt[(scol + j) * 64 + srow]      = v0[j];
      Vt[(scol + j) * 64 + srow + 32] = v1[j];
    }
    __syncthreads();

    f32x4 s[4];
#pragma unroll
    for (int n = 0; n < 4; n++){
      s[n] = (f32x4){0, 0, 0, 0};
#pragma unroll
      for (int ks = 0; ks < 2; ks++){
        bf16x8 kf = __builtin_bit_cast(bf16x8,
            *(const us8*)&Ks[(n * 16 + lr) * 64 + ks * 32 + lg * 8]);
        s[n] = __builtin_amdgcn_mfma_f32_16x16x32_bf16(qf[ks], kf, s[n], 0, 0, 0);
      }
    }

    float sv[4][4];
    float tmax[4] = {-1e30f, -1e30f, -1e30f, -1e30f};
    const bool diag = (kt == qt);
#pragma unroll
    for (int n = 0; n < 4; n++)
#pragma unroll
      for (int r = 0; r < 4; r++){
        float x = s[n][r] * scale;
        if (diag && (n * 16 + lr) > (wave * 16 + lg * 4 + r)) x = -1e30f;
        sv[n][r] = x;
        tmax[r] = fmaxf(tmax[r], x);
      }
#pragma unroll
    for (int off = 1; off < 16; off <<= 1)
#pragma unroll
      for (int r = 0; r < 4; r++) tmax[r] = fmaxf(tmax[r], __shfl_xor(tmax[r], off));

    float alpha[4], psum[4];
#pragma unroll
    for (int r = 0; r < 4; r++){
      float mn = fmaxf(m_run[r], tmax[r]);
      alpha[r] = __expf(m_run[r] - mn);
      m_run[r] = mn;
      psum[r] = 0.f;
    }
    float p[4][4];
#pragma unroll
    for (int n = 0; n < 4; n++)
#pragma unroll
      for (int r = 0; r < 4; r++){ p[n][r] = __expf(sv[n][r] - m_run[r]); psum[r] += p[n][r]; }
#pragma unroll
    for (int off = 1; off < 16; off <<= 1)
#pragma unroll
      for (int r = 0; r < 4; r++) psum[r] += __shfl_xor(psum[r], off);
#pragma unroll
    for (int r = 0; r < 4; r++) l_run[r] = l_run[r] * alpha[r] + psum[r];
#pragma unroll
    for (int nd = 0; nd < 4; nd++)
#pragma unroll
      for (int r = 0; r < 4; r++) acc_o[nd][r] *= alpha[r];

#pragma unroll
    for (int n = 0; n < 4; n++)
#pragma unroll
      for (int r = 0; r < 4; r++)
        Ps[wave][(lg * 4 + r) * 64 + n * 16 + lr] = f2bf(p[n][r]);
    asm volatile("s_waitcnt lgkmcnt(0)" ::: "memory");
    bf16x8 pa[2];
    pa[0] = __builtin_bit_cast(bf16x8, *(const us8*)&Ps[wave][lr * 64 + lg * 8]);
    pa[1] = __builtin_bit_cast(bf16x8, *(const us8*)&Ps[wave][lr * 64 + 32 + lg * 8]);
#pragma unroll
    for (int nd = 0; nd < 4; nd++)
#pragma unroll
      for (int ks = 0; ks < 2; ks++){
        bf16x8 vf = __builtin_bit_cast(bf16x8,
            *(const us8*)&Vt[(nd * 16 + lr) * 64 + ks * 32 + lg * 8]);
        acc_o[nd] = __builtin_amdgcn_mfma_f32_16x16x32_bf16(pa[ks], vf, acc_o[nd], 0, 0, 0);
      }
    __syncthreads();
  }

  float inv[4];
#pragma unroll
  for (int r = 0; r < 4; r++) inv[r] = 1.f / l_run[r];
#pragma unroll
  for (int nd = 0; nd < 4; nd++)
#pragma unroll
    for (int r = 0; r < 4; r++){
      const int row_t = qt * 64 + wave * 16 + lg * 4 + r;
      y[(rowbase + row_t) * HDIM + h * HEADD + nd * 16 + lr] = f2bf(acc_o[nd][r] * inv[r]);
    }
}

// ---------------- launch ----------------
extern "C" void kernel_launch(void* const* d_in, const int* in_sizes, int n_in,
                              void* d_out, int out_size, void* d_ws, size_t ws_size,
                              hipStream_t stream)
{
  const int*   ixs  = (const int*)  d_in[0];
  const float* tok  = (const float*)d_in[1];
  const float* pos  = (const float*)d_in[2];
  const float* Wprj = (const float*)d_in[3];
  const float* Wq   = (const float*)d_in[4];
  const float* bq_  = (const float*)d_in[5];
  const float* Wk   = (const float*)d_in[6];
  const float* bk_  = (const float*)d_in[7];
  const float* Wv   = (const float*)d_in[8];
  const float* bv_  = (const float*)d_in[9];
  const float* W1   = (const float*)d_in[10];
  const float* b1_  = (const float*)d_in[11];
  const float* W2   = (const float*)d_in[12];
  const float* b2_  = (const float*)d_in[13];
  float* out = (float*)d_out;

  ushort_t* ws    = (ushort_t*)d_ws;
  ushort_t* x0    = ws;                          // 4096*512
  ushort_t* x1    = x0    + 2097152;
  ushort_t* qkv   = x1    + 2097152;             // 4096*1536
  ushort_t* yb    = qkv   + 6291456;
  ushort_t* h1b   = yb    + 2097152;
  ushort_t* wprjb = h1b   + 2097152;             // fused arena [Wprj|Wq|Wk|Wv|W1|W2]
  ushort_t* wqkvb = wprjb + 262144;
  ushort_t* w1b   = wqkvb + 786432;
  ushort_t* w2b   = w1b   + 262144;              // 32000*512
  float*    bqkv  = (float*)(w2b + 16384000);    // 1536 f32

  cvt_all_kernel<<<2048, 256, 0, stream>>>(Wprj, Wq, Wk, Wv, W1, W2,
                                           bq_, bk_, bv_, wprjb, bqkv);

  embed_kernel<<<NROWS, 256, 0, stream>>>(ixs, tok, pos, x0);

  // x1 = x0 @ Wprj^T
  gemm2_kernel<0,0,0><<<32 * 4,   256, 0, stream>>>(x0,  wprjb, nullptr, x1,  NROWS, 512,   512);
  // qkv (fused q|k|v, N=1536)
  gemm2_kernel<1,0,0><<<32 * 12,  256, 0, stream>>>(x1,  wqkvb, bqkv,    qkv, NROWS, 1536,  512);
  // attention
  attn_kernel<<<dim3(32, 16), 256, 0, stream>>>(qkv, yb);
  // h1 = relu(y @ W1^T + b1)
  gemm2_kernel<1,1,0><<<32 * 4,   256, 0, stream>>>(yb,  w1b,   b1_,     h1b, NROWS, 512,   512);
  // out = relu(h1 @ W2^T + b2) -> f32 (256^2, 8-phase-style, counted vmcnt)
  gemm_big_kernel<<<2000, 512, 0, stream>>>(h1b, w2b, b2_, out);
}

// Round 10
// 416.393 us; speedup vs baseline: 1.1158x; 1.1158x over previous
//
#include <hip/hip_runtime.h>
#include <stdint.h>
#include <stddef.h>

#define TSEQ   2048
#define HDIM   512
#define NHEADS 8
#define HEADD  64
#define NVOCAB 32000
#define NROWS  4096   // B*T

typedef unsigned short ushort_t;
typedef __bf16 bf16x8 __attribute__((ext_vector_type(8)));
typedef float  f32x4  __attribute__((ext_vector_type(4)));
typedef unsigned short us8 __attribute__((ext_vector_type(8)));
typedef unsigned short us4 __attribute__((ext_vector_type(4)));
typedef unsigned short us2 __attribute__((ext_vector_type(2)));

__device__ __forceinline__ ushort_t f2bf(float f){
  union { float f; unsigned int u; } v; v.f = f;
  unsigned int u = v.u;
  u += 0x7FFFu + ((u >> 16) & 1u);   // RNE
  return (ushort_t)(u >> 16);
}

__device__ __forceinline__ void gload_lds16(const ushort_t* g, ushort_t* l){
  __builtin_amdgcn_global_load_lds(
      (const __attribute__((address_space(1))) void*)g,
      (__attribute__((address_space(3))) void*)l, 16, 0, 0);
}

// ---------------- fused f32 -> bf16 convert of all weights + bias concat ----------------
#define CVT_N4   4423680   // 5*65536 + 4096000
#define CVT_TOT  4424064   // + 384
__global__ void cvt_all_kernel(const float* __restrict__ Wprj, const float* __restrict__ Wq,
                               const float* __restrict__ Wk,   const float* __restrict__ Wv,
                               const float* __restrict__ W1,   const float* __restrict__ W2,
                               const float* __restrict__ bq,   const float* __restrict__ bk,
                               const float* __restrict__ bv,
                               ushort_t* __restrict__ wdst, float* __restrict__ bqkv){
  int stride = gridDim.x * blockDim.x;
  for (int i = blockIdx.x * blockDim.x + threadIdx.x; i < CVT_TOT; i += stride){
    if (i < CVT_N4){
      const float* src; int j;
      if (i < 327680){                       // the five 512x512 weights
        int w = i >> 16;                     // 0..4
        j = i & 65535;
        src = (w == 0) ? Wprj : (w == 1) ? Wq : (w == 2) ? Wk : (w == 3) ? Wv : W1;
      } else {
        j = i - 327680;
        src = W2;
      }
      float4 f = ((const float4*)src)[j];
      us4 o;
      o[0] = f2bf(f.x); o[1] = f2bf(f.y); o[2] = f2bf(f.z); o[3] = f2bf(f.w);
      ((us4*)wdst)[i] = o;
    } else {
      int j = i - CVT_N4;                    // 0..383 float4 of bqkv
      const float* src = (j < 128) ? bq : (j < 256) ? bk : bv;
      int jj = j & 127;
      ((float4*)bqkv)[j] = ((const float4*)src)[jj];
    }
  }
}

// ---------------- embedding: x0 = tok[ix] + pos ----------------
__global__ void embed_kernel(const int* __restrict__ ixs, const float* __restrict__ tok,
                             const float* __restrict__ pos, ushort_t* __restrict__ x0){
  const int r = blockIdx.x;            // 0..4095 (b*T + t)
  const int t = r & (TSEQ - 1);
  const int ix = ixs[r];
  const int j = threadIdx.x;           // 0..255, 2 floats each
  const float2 a = ((const float2*)(tok + (size_t)ix * HDIM))[j];
  const float2 p = ((const float2*)(pos + (size_t)t * HDIM))[j];
  us2 o; o[0] = f2bf(a.x + p.x); o[1] = f2bf(a.y + p.y);
  *(us2*)(x0 + (size_t)r * HDIM + j * 2) = o;
}

// ---------------- small GEMM: C[M,N] = A[M,K] @ W[N,K]^T (+bias)(+relu) ----------------
// 128x128 tile, BK=64, double-buffered LDS, XOR chunk swizzle (conflicts=0 per r5).
// MFMA operands SWAPPED (mfma(bfr, af)): lane holds 4 consecutive output columns
// -> vectorized us4/f32x4 epilogue. (Verified passing r6/r8/r9.)
template<int HAS_BIAS, int RELU, int OUT_F32>
__global__ __launch_bounds__(256) void gemm2_kernel(
    const ushort_t* __restrict__ A, const ushort_t* __restrict__ W,
    const float* __restrict__ bias, void* __restrict__ outp,
    int M, int N, int K)
{
  __shared__ ushort_t As[2][128 * 64];
  __shared__ ushort_t Bs[2][128 * 64];
  const int tid  = threadIdx.x;
  const int wave = tid >> 6;
  const int lane = tid & 63;
  const int lr   = lane & 15;
  const int lg   = lane >> 4;
  const int wr   = wave >> 1, wc = wave & 1;

  const int nwg = gridDim.x;
  const int cpx = nwg >> 3;                    // blocks per XCD chunk
  const int g   = (blockIdx.x & 7) * cpx + (blockIdx.x >> 3);
  const int nby = M >> 7;
  const int by  = g % nby;
  const int bx  = g / nby;
  const int row0 = by << 7;
  const int col0 = bx << 7;

  f32x4 acc[4][4];
#pragma unroll
  for (int m = 0; m < 4; m++)
#pragma unroll
    for (int n = 0; n < 4; n++) acc[m][n] = (f32x4){0.f, 0.f, 0.f, 0.f};

  const int e    = tid * 8;
  const int srow = e >> 6;
  const int gch  = (((e & 63) >> 3) ^ (srow & 7)) * 8;
  const ushort_t* gA = A + (size_t)(row0 + srow) * K + gch;
  const ushort_t* gB = W + (size_t)(col0 + srow) * K + gch;
  const int ldsoff = wave * 512;

#pragma unroll
  for (int p = 0; p < 4; p++){
    gload_lds16(gA + (size_t)(p * 32) * K, &As[0][p * 2048 + ldsoff]);
    gload_lds16(gB + (size_t)(p * 32) * K, &Bs[0][p * 2048 + ldsoff]);
  }
  __syncthreads();

  const int NT = K >> 6;
  for (int t = 0; t < NT; ++t){
    const int cur = t & 1;
    if (t + 1 < NT){
      const int ko = (t + 1) << 6;
#pragma unroll
      for (int p = 0; p < 4; p++){
        gload_lds16(gA + (size_t)(p * 32) * K + ko, &As[cur ^ 1][p * 2048 + ldsoff]);
        gload_lds16(gB + (size_t)(p * 32) * K + ko, &Bs[cur ^ 1][p * 2048 + ldsoff]);
      }
    }
#pragma unroll
    for (int kk = 0; kk < 64; kk += 32){
      const int rch = (((kk >> 3) + lg) ^ (lr & 7)) * 8;   // swizzled read chunk
      bf16x8 af[4], bfr[4];
#pragma unroll
      for (int m = 0; m < 4; m++)
        af[m] = __builtin_bit_cast(bf16x8,
            *(const us8*)&As[cur][(wr * 64 + m * 16 + lr) * 64 + rch]);
#pragma unroll
      for (int n = 0; n < 4; n++)
        bfr[n] = __builtin_bit_cast(bf16x8,
            *(const us8*)&Bs[cur][(wc * 64 + n * 16 + lr) * 64 + rch]);
#pragma unroll
      for (int m = 0; m < 4; m++)
#pragma unroll
        for (int n = 0; n < 4; n++)
          acc[m][n] = __builtin_amdgcn_mfma_f32_16x16x32_bf16(bfr[n], af[m], acc[m][n], 0, 0, 0);
    }
    __syncthreads();
  }

  // epilogue: lane holds rows (wr*64+m*16+lr), cols (wc*64+n*16+lg*4 .. +3)
#pragma unroll
  for (int n = 0; n < 4; n++){
    const int colb = col0 + wc * 64 + n * 16 + lg * 4;
    f32x4 b4 = (f32x4){0.f, 0.f, 0.f, 0.f};
    if (HAS_BIAS) b4 = *(const f32x4*)&bias[colb];
#pragma unroll
    for (int m = 0; m < 4; m++){
      const int row = row0 + wr * 64 + m * 16 + lr;
      float v0 = acc[m][n][0] + b4[0], v1 = acc[m][n][1] + b4[1];
      float v2 = acc[m][n][2] + b4[2], v3 = acc[m][n][3] + b4[3];
      if (RELU){ v0 = fmaxf(v0,0.f); v1 = fmaxf(v1,0.f); v2 = fmaxf(v2,0.f); v3 = fmaxf(v3,0.f); }
      if (OUT_F32){
        f32x4 o = {v0, v1, v2, v3};
        *(f32x4*)&((float*)outp)[(size_t)row * N + colb] = o;
      } else {
        us4 o; o[0] = f2bf(v0); o[1] = f2bf(v1); o[2] = f2bf(v2); o[3] = f2bf(v3);
        *(us4*)&((ushort_t*)outp)[(size_t)row * N + colb] = o;
      }
    }
  }
}

// ---------------- vocab GEMM: out = relu(A[4096,512] @ W2[32000,512]^T + b2), f32 ----------------
// Measured-best r4 structure, unchanged: 256x256 tile, BK=32 (16 K-tiles), 8 waves,
// triple-buffered LDS (96 KB, 1 block/CU), depth-2 prefetch, counted vmcnt(4),
// 2 phases/K-tile with raw s_barrier + setprio.
// r10 A/B vs r8: ONLY the block mapping differs (r4's by-inner: 16 consecutive
// blocks share one W2 col-panel and run concurrently -> panel read ~once via L3;
// r8's XCD-stripe regressed). NT f32x4 stores retained from r8 (write stream
// bypasses caches -> should stop the 524 MB output from cycling L3 and evicting W2).
#define NKT 16
__global__ __launch_bounds__(512, 2) void gemm_big_kernel(
    const ushort_t* __restrict__ A, const ushort_t* __restrict__ W,
    const float* __restrict__ bias, float* __restrict__ outp)
{
  __shared__ ushort_t Asb[3][256 * 32];
  __shared__ ushort_t Bsb[3][256 * 32];
  const int K = HDIM, N = NVOCAB;
  const int tid  = threadIdx.x;
  const int wave = tid >> 6;            // 0..7
  const int lane = tid & 63;
  const int lr   = lane & 15;
  const int lg   = lane >> 4;
  const int wr   = wave >> 2;           // 0..1 (M)
  const int wc   = wave & 3;            // 0..3 (N)
  const int by   = blockIdx.x & 15;     // by-inner: 16 consecutive blocks = one col-panel
  const int bx   = blockIdx.x >> 4;     // 0..124
  const int row0 = by << 8;
  const int col0 = bx << 8;

  const int rA   = tid >> 2;            // 0..127
  const int csw  = ((tid & 3) ^ (rA & 3) ^ ((rA >> 2) & 3)) * 8;
  const int swzc = (lg ^ (lr & 3) ^ ((lr >> 2) & 3)) * 8;

  f32x4 acc[8][4];
#pragma unroll
  for (int m = 0; m < 8; m++)
#pragma unroll
    for (int n = 0; n < 4; n++) acc[m][n] = (f32x4){0.f, 0.f, 0.f, 0.f};

  // ---- prologue: stage tiles 0 and 1, wait for tile 0 ----
  {
    const ushort_t* gA = A + (size_t)(row0 + rA) * K + csw;
    const ushort_t* gW = W + (size_t)(col0 + rA) * K + csw;
#pragma unroll
    for (int t = 0; t < 2; t++){
      gload_lds16(gA + t * 32,                       &Asb[t][wave * 512]);
      gload_lds16(gA + (size_t)128 * K + t * 32,     &Asb[t][4096 + wave * 512]);
      gload_lds16(gW + t * 32,                       &Bsb[t][wave * 512]);
      gload_lds16(gW + (size_t)128 * K + t * 32,     &Bsb[t][4096 + wave * 512]);
    }
  }
  asm volatile("s_waitcnt vmcnt(4)" ::: "memory");
  __builtin_amdgcn_s_barrier();

  for (int t = 0; t < NKT; ++t){
    const ushort_t* Ac = &Asb[t % 3][0];
    const ushort_t* Bc = &Bsb[t % 3][0];
    ushort_t* An = &Asb[(t + 2) % 3][0];
    ushort_t* Bn = &Bsb[(t + 2) % 3][0];
    const bool pf = (t + 2 < NKT);
    const int kg = (t + 2) * 32;

    // ---------- phase 0: B-frags + A-frags m0..3 ; stage A of tile t+2 ----------
    bf16x8 bfr[4], af[4];
#pragma unroll
    for (int n = 0; n < 4; n++)
      bfr[n] = __builtin_bit_cast(bf16x8,
          *(const us8*)&Bc[(wc * 64 + n * 16 + lr) * 32 + swzc]);
#pragma unroll
    for (int q = 0; q < 4; q++)
      af[q] = __builtin_bit_cast(bf16x8,
          *(const us8*)&Ac[(wr * 128 + q * 16 + lr) * 32 + swzc]);
    if (pf){
      gload_lds16(A + (size_t)(row0 + rA) * K + kg + csw,       An + wave * 512);
      gload_lds16(A + (size_t)(row0 + rA + 128) * K + kg + csw, An + 4096 + wave * 512);
    }
    __builtin_amdgcn_s_barrier();
    asm volatile("s_waitcnt lgkmcnt(0)" ::: "memory");
    __builtin_amdgcn_sched_barrier(0);
    __builtin_amdgcn_s_setprio(1);
#pragma unroll
    for (int q = 0; q < 4; q++)
#pragma unroll
      for (int n = 0; n < 4; n++)
        acc[q][n] = __builtin_amdgcn_mfma_f32_16x16x32_bf16(bfr[n], af[q], acc[q][n], 0, 0, 0);
    __builtin_amdgcn_s_setprio(0);
    __builtin_amdgcn_sched_barrier(0);
    __builtin_amdgcn_s_barrier();

    // ---------- phase 1: A-frags m4..7 ; stage B of tile t+2 ----------
#pragma unroll
    for (int q = 0; q < 4; q++)
      af[q] = __builtin_bit_cast(bf16x8,
          *(const us8*)&Ac[(wr * 128 + (q + 4) * 16 + lr) * 32 + swzc]);
    if (pf){
      gload_lds16(W + (size_t)(col0 + rA) * K + kg + csw,       Bn + wave * 512);
      gload_lds16(W + (size_t)(col0 + rA + 128) * K + kg + csw, Bn + 4096 + wave * 512);
    }
    __builtin_amdgcn_s_barrier();
    asm volatile("s_waitcnt lgkmcnt(0)" ::: "memory");
    __builtin_amdgcn_sched_barrier(0);
    __builtin_amdgcn_s_setprio(1);
#pragma unroll
    for (int q = 0; q < 4; q++)
#pragma unroll
      for (int n = 0; n < 4; n++)
        acc[q + 4][n] = __builtin_amdgcn_mfma_f32_16x16x32_bf16(bfr[n], af[q], acc[q + 4][n], 0, 0, 0);
    __builtin_amdgcn_s_setprio(0);
    __builtin_amdgcn_sched_barrier(0);
    if (t < NKT - 2) { asm volatile("s_waitcnt vmcnt(4)" ::: "memory"); }
    else             { asm volatile("s_waitcnt vmcnt(0)" ::: "memory"); }
    __builtin_amdgcn_s_barrier();
  }

  // ---- epilogue: f32x4 NON-TEMPORAL stores (bypass caches; output never re-read) ----
#pragma unroll
  for (int n = 0; n < 4; n++){
    const int colb = col0 + wc * 64 + n * 16 + lg * 4;
    const f32x4 b4 = *(const f32x4*)&bias[colb];
#pragma unroll
    for (int m = 0; m < 8; m++){
      const int row = row0 + wr * 128 + m * 16 + lr;
      f32x4 o;
      o[0] = fmaxf(acc[m][n][0] + b4[0], 0.f);
      o[1] = fmaxf(acc[m][n][1] + b4[1], 0.f);
      o[2] = fmaxf(acc[m][n][2] + b4[2], 0.f);
      o[3] = fmaxf(acc[m][n][3] + b4[3], 0.f);
      __builtin_nontemporal_store(o, (f32x4*)&outp[(size_t)row * N + colb]);
    }
  }
}

// ---------------- fused causal flash attention ----------------
// Heavy-first dispatch: qt = 31 - blockIdx.x (32:1 causal work spread).
__global__ __launch_bounds__(256) void attn_kernel(
    const ushort_t* __restrict__ qkv, ushort_t* __restrict__ y)
{
  __shared__ ushort_t Ks[64 * 64];
  __shared__ ushort_t Vt[64 * 64];     // transposed: [d][key]
  __shared__ ushort_t Ps[4][16 * 64];
  const int qt   = 31 - blockIdx.x;
  const int hb   = blockIdx.y;
  const int b    = hb >> 3;
  const int h    = hb & 7;
  const int tid  = threadIdx.x;
  const int wave = tid >> 6, lane = tid & 63;
  const int lr   = lane & 15, lg = lane >> 4;
  const int ld   = 3 * HDIM;
  const size_t rowbase = (size_t)b * TSEQ;
  const ushort_t* kb = qkv + HDIM;
  const ushort_t* vb = qkv + 2 * HDIM;

  const int qrow = qt * 64 + wave * 16 + lr;
  const ushort_t* qp = qkv + (rowbase + qrow) * ld + h * HEADD;
  bf16x8 qf[2];
  qf[0] = __builtin_bit_cast(bf16x8, *(const us8*)&qp[lg * 8]);
  qf[1] = __builtin_bit_cast(bf16x8, *(const us8*)&qp[32 + lg * 8]);

  float m_run[4], l_run[4];
  f32x4 acc_o[4];
#pragma unroll
  for (int i = 0; i < 4; i++){ m_run[i] = -1e30f; l_run[i] = 0.f; acc_o[i] = (f32x4){0,0,0,0}; }

  const int e    = tid * 8;
  const int srow = e >> 6;
  const int scol = e & 63;
  const float scale = 0.04419417382415922f;   // 1/sqrt(512) (full H per reference!)

  for (int kt = 0; kt <= qt; ++kt){
    const ushort_t* gK = kb + (rowbase + kt * 64 + srow) * ld + h * HEADD + scol;
    gload_lds16(gK,                     &Ks[wave * 512]);
    gload_lds16(gK + (size_t)32 * ld,   &Ks[2048 + wave * 512]);
    const ushort_t* gV = vb + (rowbase + kt * 64 + srow) * ld + h * HEADD + scol;
    us8 v0 = *(const us8*)gV;
    us8 v1 = *(const us8*)(gV + (size_t)32 * ld);
#pragma unroll
    for (int j = 0; j < 8; j++){
      Vt[(scol + j) * 64 + srow]      = v0[j];
      Vt[(scol + j) * 64 + srow + 32] = v1[j];
    }
    __syncthreads();

    f32x4 s[4];
#pragma unroll
    for (int n = 0; n < 4; n++){
      s[n] = (f32x4){0, 0, 0, 0};
#pragma unroll
      for (int ks = 0; ks < 2; ks++){
        bf16x8 kf = __builtin_bit_cast(bf16x8,
            *(const us8*)&Ks[(n * 16 + lr) * 64 + ks * 32 + lg * 8]);
        s[n] = __builtin_amdgcn_mfma_f32_16x16x32_bf16(qf[ks], kf, s[n], 0, 0, 0);
      }
    }

    float sv[4][4];
    float tmax[4] = {-1e30f, -1e30f, -1e30f, -1e30f};
    const bool diag = (kt == qt);
#pragma unroll
    for (int n = 0; n < 4; n++)
#pragma unroll
      for (int r = 0; r < 4; r++){
        float x = s[n][r] * scale;
        if (diag && (n * 16 + lr) > (wave * 16 + lg * 4 + r)) x = -1e30f;
        sv[n][r] = x;
        tmax[r] = fmaxf(tmax[r], x);
      }
#pragma unroll
    for (int off = 1; off < 16; off <<= 1)
#pragma unroll
      for (int r = 0; r < 4; r++) tmax[r] = fmaxf(tmax[r], __shfl_xor(tmax[r], off));

    float alpha[4], psum[4];
#pragma unroll
    for (int r = 0; r < 4; r++){
      float mn = fmaxf(m_run[r], tmax[r]);
      alpha[r] = __expf(m_run[r] - mn);
      m_run[r] = mn;
      psum[r] = 0.f;
    }
    float p[4][4];
#pragma unroll
    for (int n = 0; n < 4; n++)
#pragma unroll
      for (int r = 0; r < 4; r++){ p[n][r] = __expf(sv[n][r] - m_run[r]); psum[r] += p[n][r]; }
#pragma unroll
    for (int off = 1; off < 16; off <<= 1)
#pragma unroll
      for (int r = 0; r < 4; r++) psum[r] += __shfl_xor(psum[r], off);
#pragma unroll
    for (int r = 0; r < 4; r++) l_run[r] = l_run[r] * alpha[r] + psum[r];
#pragma unroll
    for (int nd = 0; nd < 4; nd++)
#pragma unroll
      for (int r = 0; r < 4; r++) acc_o[nd][r] *= alpha[r];

#pragma unroll
    for (int n = 0; n < 4; n++)
#pragma unroll
      for (int r = 0; r < 4; r++)
        Ps[wave][(lg * 4 + r) * 64 + n * 16 + lr] = f2bf(p[n][r]);
    asm volatile("s_waitcnt lgkmcnt(0)" ::: "memory");
    bf16x8 pa[2];
    pa[0] = __builtin_bit_cast(bf16x8, *(const us8*)&Ps[wave][lr * 64 + lg * 8]);
    pa[1] = __builtin_bit_cast(bf16x8, *(const us8*)&Ps[wave][lr * 64 + 32 + lg * 8]);
#pragma unroll
    for (int nd = 0; nd < 4; nd++)
#pragma unroll
      for (int ks = 0; ks < 2; ks++){
        bf16x8 vf = __builtin_bit_cast(bf16x8,
            *(const us8*)&Vt[(nd * 16 + lr) * 64 + ks * 32 + lg * 8]);
        acc_o[nd] = __builtin_amdgcn_mfma_f32_16x16x32_bf16(pa[ks], vf, acc_o[nd], 0, 0, 0);
      }
    __syncthreads();
  }

  float inv[4];
#pragma unroll
  for (int r = 0; r < 4; r++) inv[r] = 1.f / l_run[r];
#pragma unroll
  for (int nd = 0; nd < 4; nd++)
#pragma unroll
    for (int r = 0; r < 4; r++){
      const int row_t = qt * 64 + wave * 16 + lg * 4 + r;
      y[(rowbase + row_t) * HDIM + h * HEADD + nd * 16 + lr] = f2bf(acc_o[nd][r] * inv[r]);
    }
}

// ---------------- launch ----------------
extern "C" void kernel_launch(void* const* d_in, const int* in_sizes, int n_in,
                              void* d_out, int out_size, void* d_ws, size_t ws_size,
                              hipStream_t stream)
{
  const int*   ixs  = (const int*)  d_in[0];
  const float* tok  = (const float*)d_in[1];
  const float* pos  = (const float*)d_in[2];
  const float* Wprj = (const float*)d_in[3];
  const float* Wq   = (const float*)d_in[4];
  const float* bq_  = (const float*)d_in[5];
  const float* Wk   = (const float*)d_in[6];
  const float* bk_  = (const float*)d_in[7];
  const float* Wv   = (const float*)d_in[8];
  const float* bv_  = (const float*)d_in[9];
  const float* W1   = (const float*)d_in[10];
  const float* b1_  = (const float*)d_in[11];
  const float* W2   = (const float*)d_in[12];
  const float* b2_  = (const float*)d_in[13];
  float* out = (float*)d_out;

  ushort_t* ws    = (ushort_t*)d_ws;
  ushort_t* x0    = ws;                          // 4096*512
  ushort_t* x1    = x0    + 2097152;
  ushort_t* qkv   = x1    + 2097152;             // 4096*1536
  ushort_t* yb    = qkv   + 6291456;
  ushort_t* h1b   = yb    + 2097152;
  ushort_t* wprjb = h1b   + 2097152;             // fused arena [Wprj|Wq|Wk|Wv|W1|W2]
  ushort_t* wqkvb = wprjb + 262144;
  ushort_t* w1b   = wqkvb + 786432;
  ushort_t* w2b   = w1b   + 262144;              // 32000*512
  float*    bqkv  = (float*)(w2b + 16384000);    // 1536 f32

  cvt_all_kernel<<<2048, 256, 0, stream>>>(Wprj, Wq, Wk, Wv, W1, W2,
                                           bq_, bk_, bv_, wprjb, bqkv);

  embed_kernel<<<NROWS, 256, 0, stream>>>(ixs, tok, pos, x0);

  // x1 = x0 @ Wprj^T
  gemm2_kernel<0,0,0><<<32 * 4,   256, 0, stream>>>(x0,  wprjb, nullptr, x1,  NROWS, 512,   512);
  // qkv (fused q|k|v, N=1536)
  gemm2_kernel<1,0,0><<<32 * 12,  256, 0, stream>>>(x1,  wqkvb, bqkv,    qkv, NROWS, 1536,  512);
  // attention
  attn_kernel<<<dim3(32, 16), 256, 0, stream>>>(qkv, yb);
  // h1 = relu(y @ W1^T + b1)
  gemm2_kernel<1,1,0><<<32 * 4,   256, 0, stream>>>(yb,  w1b,   b1_,     h1b, NROWS, 512,   512);
  // out = relu(h1 @ W2^T + b2) -> f32 (r4 structure, by-inner mapping, NT stores)
  gemm_big_kernel<<<2000, 512, 0, stream>>>(h1b, w2b, b2_, out);
}